// Round 6
// baseline (862.529 us; speedup 1.0000x reference)
//
#include <hip/hip_runtime.h>
#include <hip/hip_bf16.h>

#define EPS 1e-6f
typedef unsigned short b16;
typedef __attribute__((ext_vector_type(8))) short v8s;
typedef __attribute__((ext_vector_type(4))) float v4f;

__device__ __forceinline__ b16 f2b(float f) {
    __hip_bfloat16 h = __float2bfloat16(f);
    return *reinterpret_cast<b16*>(&h);
}
__device__ __forceinline__ float siluf(float x){ return x / (1.f + __expf(-x)); }

// 64-lane sum reduce: levels 1,2,4,8 on VALU (DPP row_ror rotation-reduce),
// xor16 via ds_swizzle, xor32 via shfl. DS ops: 2 (vs 6 for full butterfly).
__device__ __forceinline__ float red64(float s) {
    int t;
    t = __builtin_amdgcn_update_dpp(0, __float_as_int(s), 0x121, 0xF, 0xF, false);
    s += __int_as_float(t);   // + ror1
    t = __builtin_amdgcn_update_dpp(0, __float_as_int(s), 0x122, 0xF, 0xF, false);
    s += __int_as_float(t);   // + ror2
    t = __builtin_amdgcn_update_dpp(0, __float_as_int(s), 0x124, 0xF, 0xF, false);
    s += __int_as_float(t);   // + ror4
    t = __builtin_amdgcn_update_dpp(0, __float_as_int(s), 0x128, 0xF, 0xF, false);
    s += __int_as_float(t);   // + ror8 -> row(16) sum in all lanes
    s += __int_as_float(__builtin_amdgcn_ds_swizzle(__float_as_int(s), 0x401F)); // xor16
    s += __shfl_xor(s, 32, 64);                                                  // xor32
    return s;
}

// ---- skip weight transpose: w [ic][128] fp32 -> [oc][ic] bf16 ----
template<int IC>
__global__ void __launch_bounds__(256) k_wt(const float* __restrict__ w, b16* __restrict__ o, int tot) {
    int i = blockIdx.x*256 + threadIdx.x;
    if (i >= tot) return;
    int ic = i % IC; int oc = (i / IC) & 127; int tap = i / (IC*128);
    o[i] = f2b(w[(tap*IC + ic)*128 + oc]);
}

// ---- conv weight blocked transpose: w [tap][ic][128] fp32 -> [tap][icb][oc][32] bf16 ----
template<int IC>
__global__ void __launch_bounds__(256) k_wtb(const float* __restrict__ w, b16* __restrict__ o, int tot) {
    int i = blockIdx.x*256 + threadIdx.x;
    if (i >= tot) return;
    constexpr int ICB = IC/32;
    int icl = i & 31;
    int oc  = (i >> 5) & 127;
    int r   = i >> 12;              // tap*ICB + icb
    int tap = r / ICB, icb = r % ICB;
    o[i] = f2b(w[(tap*IC + icb*32 + icl)*128 + oc]);
}

// ---- A: LN(64)+affine+silu+mask, 2x2x2 masked mean pool; h -> padded buffer ----
__global__ void __launch_bounds__(256) k_ln_down(
    const float* __restrict__ feats, const int* __restrict__ mask,
    const float* __restrict__ gamma, const float* __restrict__ beta,
    b16* __restrict__ h_ds_pad, b16* __restrict__ x_ds, float* __restrict__ cnt_out)
{
    int wave = (blockIdx.x * 256 + threadIdx.x) >> 6;   // cell id, 0..131071
    int lane = threadIdx.x & 63;
    int x = wave & 31, y = (wave >> 5) & 31, z = (wave >> 10) & 31, b = wave >> 15;
    float g = gamma[lane], be = beta[lane];
    float hacc = 0.f, xacc = 0.f, cnt = 0.f;
    #pragma unroll
    for (int i = 0; i < 8; ++i) {
        int zz = 2*z + (i>>2), yy = 2*y + ((i>>1)&1), xx = 2*x + (i&1);
        int vox = ((b*64 + zz)*64 + yy)*64 + xx;
        int m = mask[vox];
        float val = feats[vox*64 + lane];
        float s1 = red64(val);
        float s2 = red64(val*val);
        float mu = s1 * (1.f/64.f);
        float var = fmaxf(s2 * (1.f/64.f) - mu*mu, 0.f);
        float h = (val - mu) * rsqrtf(var + EPS) * g + be;
        h = siluf(h);
        if (m != 0) { hacc += h; xacc += val; cnt += 1.f; }
    }
    float inv = 1.f / fmaxf(cnt, 1.f);
    long vp = ((long)(b*34 + z+1)*34 + (y+1))*34 + (x+1);
    h_ds_pad[vp*64 + lane] = f2b(hacc * inv);
    x_ds[(long)wave*64 + lane] = f2b(xacc * inv);
    if (lane == 0) cnt_out[wave] = cnt;
}

// ---- MFMA implicit-GEMM conv: BM=256, double-buffered LDS, 1 barrier/step ----
// block = 256 thr = 4 waves; C-tile M=256 (8 y-rows x 32 x), N=128 oc.
// Wave w owns 64 rows (2 y-rows) x 128 oc: 4x8 accumulator, 32 MFMA per K-step.
// LDS bytes/MFMA cut 36% vs BM=128 (12 ds_reads per 32 MFMA vs 10 per 16).
// Reg-staged ping-pong: global loads issued FIRST in each half-step (full-step
// latency cover), ds_writes to the non-compute buffer, ONE barrier per step.
template<int IC, bool IS_CONV1>
__device__ __forceinline__ void conv_body(
    const b16* __restrict__ inp,      // padded [b][34][34][34][IC] bf16
    const b16* __restrict__ wt,       // [tap][icb][128 oc][32 ic] bf16
    const float* __restrict__ bias,
    const float* __restrict__ cnt,
    const b16* __restrict__ x_ds,     // conv2 only: [cell][64]
    const b16* __restrict__ wst,      // conv2 only: [128 oc][64 ic]
    const float* __restrict__ b_skip, // conv2 only
    b16* __restrict__ h2out,          // conv1: padded bf16 out
    float* __restrict__ out)          // conv2: fp32 out [cell][128]
{
    constexpr int ICB = IC/32;
    constexpr int NK = 27*ICB;        // 54 / 108, even
    __shared__ b16 lA[2][8192];       // 2 x 16 KB: [v(256)][32ic], chunk-rotated
    __shared__ b16 lB[2][4096];       // 2 x 8 KB : [oc(128)][32ic], chunk-rotated

    // XCD-aware bijective swizzle (512 blocks, 8 XCDs, 64-block chunks)
    int bid = ((blockIdx.x & 7) << 6) | (blockIdx.x >> 3);
    int y0 = (bid & 3) << 3;          // 4 y-groups of 8 rows
    int z  = (bid >> 2) & 31;
    int b  = bid >> 7;
    int t  = threadIdx.x;
    int lane = t & 63;
    int w = t >> 6;
    int col = lane & 15;
    int quad = lane >> 4;

    // --- staging coords: thread t owns voxel v=t (4x16B) + oc-row pair (2x16B) ---
    const b16* gA = inp + ((long)((b*34 + z)*34 + (y0 + (t>>5)))*34 + (t&31))*IC;
    int rotA = ((t & 31) >> 1) & 3;
    int wA[4];
    #pragma unroll
    for (int c = 0; c < 4; ++c) wA[c] = t*32 + ((c + rotA) & 3)*8;

    int ocs = t >> 1, bc = (t & 1) << 1;
    const b16* gB = wt + ocs*32 + bc*8;
    int rotB = (ocs & 15) >> 1;
    int wB0 = ocs*32 + ((bc     + rotB) & 3)*8;
    int wB1 = ocs*32 + ((bc + 1 + rotB) & 3)*8;

    // --- fragment read offsets (r0-verified mapping; tile bases multiples of 16
    //     keep slot = (quad + (col>>1))&3 invariant) ---
    int so   = ((quad + (col>>1)) & 3) * 8;
    int aoff = w*2048 + col*32 + so;
    int boff = col*32 + so;

    v4f acc[4][8];
    #pragma unroll
    for (int r=0;r<4;++r)
        #pragma unroll
        for (int n=0;n<8;++n) acc[r][n] = (v4f){0.f,0.f,0.f,0.f};

    // --- tap-walk recurrence for A offsets (uniform, no divides) ---
    long offA = 0;
    int icbn = 0, kxn = 0, kyn = 0;
    auto advance = [&]() {
        ++icbn; offA += 32;
        if (icbn == ICB) {
            icbn = 0;
            ++kxn;
            if (kxn == 3) {
                kxn = 0; ++kyn;
                if (kyn == 3) { kyn = 0; offA += (long)(34*34 - 2*34 - 3)*IC; }
                else          {           offA += (long)(34 - 3)*IC; }
            }
        }
    };

    auto gload = [&](long oA, long oB, v8s (&SA)[4], v8s (&SB)[2]) {
        #pragma unroll
        for (int c = 0; c < 4; ++c) SA[c] = *(const v8s*)(gA + oA + c*8);
        SB[0] = *(const v8s*)(gB + oB);
        SB[1] = *(const v8s*)(gB + oB + 8);
    };
    auto lwrite = [&](int buf, const v8s (&SA)[4], const v8s (&SB)[2]) {
        #pragma unroll
        for (int c = 0; c < 4; ++c) *(v8s*)(&lA[buf][wA[c]]) = SA[c];
        *(v8s*)(&lB[buf][wB0]) = SB[0];
        *(v8s*)(&lB[buf][wB1]) = SB[1];
    };
    auto compute = [&](int buf) {
        v8s a[4];
        #pragma unroll
        for (int r = 0; r < 4; ++r) a[r] = *(const v8s*)(&lA[buf][aoff + r*512]);
        #pragma unroll
        for (int n = 0; n < 8; ++n) {
            v8s bb = *(const v8s*)(&lB[buf][n*512 + boff]);
            #pragma unroll
            for (int r = 0; r < 4; ++r)
                acc[r][n] = __builtin_amdgcn_mfma_f32_16x16x32_bf16(a[r], bb, acc[r][n], 0,0,0);
        }
    };

    v8s sA0[4], sB0[2], sA1[4], sB1[2];

    // prologue: data(0) -> buf0; data(1) -> regs
    gload(0, 0, sA0, sB0);          advance();
    lwrite(0, sA0, sB0);
    gload(offA, 4096, sA1, sB1);    advance();
    __syncthreads();

    for (int k = 0; k < NK; k += 2) {
        // half-step even (kk = k): compute buf0, write data(k+1)->buf1
        if (k + 2 < NK) { gload(offA, (long)(k+2) << 12, sA0, sB0); advance(); }
        lwrite(1, sA1, sB1);
        compute(0);
        __syncthreads();
        // half-step odd (kk = k+1): compute buf1, write data(k+2)->buf0
        if (k + 3 < NK) { gload(offA, (long)(k+3) << 12, sA1, sB1); advance(); }
        if (k + 2 < NK) lwrite(0, sA0, sB0);
        compute(1);
        if (k + 2 < NK) __syncthreads();
    }

    long zrow = (long)(b*32 + z)*32;

    if (!IS_CONV1) {
        // skip GEMM: x_ds[cell][64] @ wst[128][64]^T folded into accumulators
        const b16* WS = wst + col*64 + quad*8;
        #pragma unroll
        for (int tr = 0; tr < 4; ++tr) {
            int yrow = y0 + 2*w + (tr >> 1);
            long cellrowR = (zrow + yrow)*32;
            const b16* X = x_ds + (cellrowR + ((tr & 1) << 4) + col)*64 + quad*8;
            #pragma unroll
            for (int s = 0; s < 2; ++s) {
                v8s a = *(const v8s*)(X + s*32);
                #pragma unroll
                for (int n = 0; n < 8; ++n) {
                    v8s bb = *(const v8s*)(WS + n*16*64 + s*32);
                    acc[tr][n] = __builtin_amdgcn_mfma_f32_16x16x32_bf16(a, bb, acc[tr][n], 0,0,0);
                }
            }
        }
    }

    float bv[8];
    #pragma unroll
    for (int n = 0; n < 8; ++n)
        bv[n] = bias[n*16+col] + (IS_CONV1 ? 0.f : b_skip[n*16+col]);

    #pragma unroll
    for (int tr = 0; tr < 4; ++tr) {
        int yrow = y0 + 2*w + (tr >> 1);
        int xbase = (tr & 1) << 4;
        long cellrowR = (zrow + yrow)*32;
        if (IS_CONV1) {
            // bias + LN(128, no affine) + silu + mask -> padded bf16
            long prowR = ((long)(b*34 + z+1)*34 + (yrow+1))*34 + 1;
            float s1[4], s2[4];
            #pragma unroll
            for (int r = 0; r < 4; ++r) {
                float a = 0.f, q = 0.f;
                #pragma unroll
                for (int n = 0; n < 8; ++n) { float v = acc[tr][n][r] + bv[n]; a += v; q += v*v; }
                s1[r] = a; s2[r] = q;
            }
            #pragma unroll
            for (int off = 1; off < 16; off <<= 1) {
                #pragma unroll
                for (int r = 0; r < 4; ++r) { s1[r] += __shfl_xor(s1[r], off); s2[r] += __shfl_xor(s2[r], off); }
            }
            #pragma unroll
            for (int r = 0; r < 4; ++r) {
                int x = xbase + quad*4 + r;
                float c = cnt[cellrowR + x];
                float mu = s1[r]*(1.f/128.f);
                float var = fmaxf(s2[r]*(1.f/128.f) - mu*mu, 0.f);
                float rs = rsqrtf(var + EPS);
                bool act = c > 0.f;
                #pragma unroll
                for (int n = 0; n < 8; ++n) {
                    float v = acc[tr][n][r] + bv[n];
                    float hv = act ? siluf((v - mu)*rs) : 0.f;
                    h2out[(prowR + x)*128 + n*16 + col] = f2b(hv);
                }
            }
        } else {
            #pragma unroll
            for (int r = 0; r < 4; ++r) {
                int x = xbase + quad*4 + r;
                float c = cnt[cellrowR + x];
                bool act = c > 0.f;
                #pragma unroll
                for (int n = 0; n < 8; ++n) {
                    float v = acc[tr][n][r] + bv[n];
                    out[(cellrowR + x)*128 + n*16 + col] = act ? v : 0.f;
                }
            }
        }
    }
}

// distinct names so rocprof separates the two convs
__global__ void __launch_bounds__(256) k_conv1(
    const b16* __restrict__ inp, const b16* __restrict__ wt,
    const float* __restrict__ bias, const float* __restrict__ cnt,
    b16* __restrict__ h2out)
{
    conv_body<64, true>(inp, wt, bias, cnt, nullptr, nullptr, nullptr, h2out, nullptr);
}

__global__ void __launch_bounds__(256) k_conv2(
    const b16* __restrict__ inp, const b16* __restrict__ wt,
    const float* __restrict__ bias, const float* __restrict__ cnt,
    const b16* __restrict__ x_ds, const b16* __restrict__ wst,
    const float* __restrict__ b_skip, float* __restrict__ out)
{
    conv_body<128, false>(inp, wt, bias, cnt, x_ds, wst, b_skip, nullptr, out);
}

extern "C" void kernel_launch(void* const* d_in, const int* in_sizes, int n_in,
                              void* d_out, int out_size, void* d_ws, size_t ws_size,
                              hipStream_t stream) {
    const float* feats  = (const float*)d_in[0];
    const int*   mask   = (const int*)  d_in[1];
    const float* gamma1 = (const float*)d_in[2];
    const float* beta1  = (const float*)d_in[3];
    const float* w1     = (const float*)d_in[4];
    const float* b1     = (const float*)d_in[5];
    const float* w2     = (const float*)d_in[6];
    const float* b2     = (const float*)d_in[7];
    const float* w_skip = (const float*)d_in[8];
    const float* b_skip = (const float*)d_in[9];
    float* out = (float*)d_out;

    char* ws = (char*)d_ws;
    b16*   h_ds_pad = (b16*)(ws);                        // 4*34^3*64*2  = 20,123,648
    b16*   h2_pad   = (b16*)(ws + 20123648);             // 4*34^3*128*2 = 40,247,296
    b16*   x_ds     = (b16*)(ws + 60370944);             // 16,777,216
    float* cnt      = (float*)(ws + 77148160);           // 524,288
    b16*   w1t      = (b16*)(ws + 77672448);             // 442,368
    b16*   w2t      = (b16*)(ws + 78114816);             // 884,736
    b16*   wst      = (b16*)(ws + 78999552);             // 16,384

    // zero halos (interior fully overwritten each launch)
    hipMemsetAsync(h_ds_pad, 0, 20123648, stream);
    hipMemsetAsync(h2_pad,   0, 40247296, stream);

    const int n_w1 = 27*64*128;    // 221184
    const int n_w2 = 27*128*128;   // 442368
    const int n_ws = 64*128;       // 8192
    k_wtb<64> <<<(n_w1 + 255)/256, 256, 0, stream>>>(w1, w1t, n_w1);
    k_wtb<128><<<(n_w2 + 255)/256, 256, 0, stream>>>(w2, w2t, n_w2);
    k_wt<64>  <<<(n_ws + 255)/256, 256, 0, stream>>>(w_skip, wst, n_ws);

    k_ln_down<<<32768, 256, 0, stream>>>(feats, mask, gamma1, beta1, h_ds_pad, x_ds, cnt);

    k_conv1<<<512, 256, 0, stream>>>(h_ds_pad, w1t, b1, cnt, h2_pad);
    k_conv2<<<512, 256, 0, stream>>>(h2_pad, w2t, b2, cnt, x_ds, wst, b_skip, out);
}

// Round 7
// 621.834 us; speedup vs baseline: 1.3871x; 1.3871x over previous
//
#include <hip/hip_runtime.h>
#include <hip/hip_bf16.h>

#define EPS 1e-6f
typedef unsigned short b16;
typedef __attribute__((ext_vector_type(8))) short v8s;
typedef __attribute__((ext_vector_type(4))) float v4f;

typedef const __attribute__((address_space(1))) void* gptr_t;
typedef __attribute__((address_space(3))) void* lptr_t;

__device__ __forceinline__ b16 f2b(float f) {
    __hip_bfloat16 h = __float2bfloat16(f);
    return *reinterpret_cast<b16*>(&h);
}
__device__ __forceinline__ float siluf(float x){ return x / (1.f + __expf(-x)); }

// async global->LDS, 16B per lane; LDS dest = wave-uniform base + lane*16
__device__ __forceinline__ void gll16(const b16* g, b16* l) {
    __builtin_amdgcn_global_load_lds((gptr_t)g, (lptr_t)l, 16, 0, 0);
}

// 64-lane sum reduce: levels 1,2,4,8 on VALU (DPP row_ror rotation-reduce),
// xor16 via ds_swizzle, xor32 via shfl.
__device__ __forceinline__ float red64(float s) {
    int t;
    t = __builtin_amdgcn_update_dpp(0, __float_as_int(s), 0x121, 0xF, 0xF, false);
    s += __int_as_float(t);   // + ror1
    t = __builtin_amdgcn_update_dpp(0, __float_as_int(s), 0x122, 0xF, 0xF, false);
    s += __int_as_float(t);   // + ror2
    t = __builtin_amdgcn_update_dpp(0, __float_as_int(s), 0x124, 0xF, 0xF, false);
    s += __int_as_float(t);   // + ror4
    t = __builtin_amdgcn_update_dpp(0, __float_as_int(s), 0x128, 0xF, 0xF, false);
    s += __int_as_float(t);   // + ror8 -> row(16) sum in all lanes
    s += __int_as_float(__builtin_amdgcn_ds_swizzle(__float_as_int(s), 0x401F)); // xor16
    s += __shfl_xor(s, 32, 64);                                                  // xor32
    return s;
}

// ---- skip weight transpose: w [ic][128] fp32 -> [oc][ic] bf16 ----
template<int IC>
__global__ void __launch_bounds__(256) k_wt(const float* __restrict__ w, b16* __restrict__ o, int tot) {
    int i = blockIdx.x*256 + threadIdx.x;
    if (i >= tot) return;
    int ic = i % IC; int oc = (i / IC) & 127; int tap = i / (IC*128);
    o[i] = f2b(w[(tap*IC + ic)*128 + oc]);
}

// ---- conv weight blocked transpose: w [tap][ic][128] fp32 -> [tap][icb][oc][32] bf16 ----
template<int IC>
__global__ void __launch_bounds__(256) k_wtb(const float* __restrict__ w, b16* __restrict__ o, int tot) {
    int i = blockIdx.x*256 + threadIdx.x;
    if (i >= tot) return;
    constexpr int ICB = IC/32;
    int icl = i & 31;
    int oc  = (i >> 5) & 127;
    int r   = i >> 12;              // tap*ICB + icb
    int tap = r / ICB, icb = r % ICB;
    o[i] = f2b(w[(tap*IC + icb*32 + icl)*128 + oc]);
}

// ---- A: LN(64)+affine+silu+mask, 2x2x2 masked mean pool; h -> padded buffer ----
__global__ void __launch_bounds__(256) k_ln_down(
    const float* __restrict__ feats, const int* __restrict__ mask,
    const float* __restrict__ gamma, const float* __restrict__ beta,
    b16* __restrict__ h_ds_pad, b16* __restrict__ x_ds, float* __restrict__ cnt_out)
{
    int wave = (blockIdx.x * 256 + threadIdx.x) >> 6;   // cell id, 0..131071
    int lane = threadIdx.x & 63;
    int x = wave & 31, y = (wave >> 5) & 31, z = (wave >> 10) & 31, b = wave >> 15;
    float g = gamma[lane], be = beta[lane];
    float hacc = 0.f, xacc = 0.f, cnt = 0.f;
    #pragma unroll
    for (int i = 0; i < 8; ++i) {
        int zz = 2*z + (i>>2), yy = 2*y + ((i>>1)&1), xx = 2*x + (i&1);
        int vox = ((b*64 + zz)*64 + yy)*64 + xx;
        int m = mask[vox];
        float val = feats[vox*64 + lane];
        float s1 = red64(val);
        float s2 = red64(val*val);
        float mu = s1 * (1.f/64.f);
        float var = fmaxf(s2 * (1.f/64.f) - mu*mu, 0.f);
        float h = (val - mu) * rsqrtf(var + EPS) * g + be;
        h = siluf(h);
        if (m != 0) { hacc += h; xacc += val; cnt += 1.f; }
    }
    float inv = 1.f / fmaxf(cnt, 1.f);
    long vp = ((long)(b*34 + z+1)*34 + (y+1))*34 + (x+1);
    h_ds_pad[vp*64 + lane] = f2b(hacc * inv);
    x_ds[(long)wave*64 + lane] = f2b(xacc * inv);
    if (lane == 0) cnt_out[wave] = cnt;
}

// ---- MFMA implicit-GEMM conv: DMA-staged double-buffer (r2-verified), 4 blk/CU ----
// block = 256 thr = 4 waves; C-tile M=128 (4 y-rows x 32 x), N=128 oc.
// global_load_lds staging frees the 32 prefetch VGPRs -> with launch_bounds
// (256,4) total regs (incl. 64 acc AGPRs, unified file) fit 128 -> 4 waves/SIMD
// -> 4 blocks/CU. The per-step vmcnt(0) barrier drain is covered by the other
// resident blocks (m114 implicit overlap). One barrier per K-step.
template<int IC, bool IS_CONV1>
__device__ __forceinline__ void conv_body(
    const b16* __restrict__ inp,      // padded [b][34][34][34][IC] bf16
    const b16* __restrict__ wt,       // [tap][icb][128 oc][32 ic] bf16
    const float* __restrict__ bias,
    const float* __restrict__ cnt,
    const b16* __restrict__ x_ds,     // conv2 only: [cell][64]
    const b16* __restrict__ wst,      // conv2 only: [128 oc][64 ic]
    const float* __restrict__ b_skip, // conv2 only
    b16* __restrict__ h2out,          // conv1: padded bf16 out
    float* __restrict__ out)          // conv2: fp32 out [cell][128]
{
    constexpr int ICB = IC/32;
    constexpr int NK = 27*ICB;
    __shared__ b16 lA[2][4096];   // 2 x 8 KB double buffer
    __shared__ b16 lB[2][4096];

    // XCD-aware bijective swizzle (1024 blocks, 8 XCDs, 128-block chunks)
    int bid = ((blockIdx.x & 7) << 7) | (blockIdx.x >> 3);
    int y0 = (bid & 7) << 2;
    int z  = (bid >> 3) & 31;
    int b  = bid >> 8;
    int t  = threadIdx.x;
    int lane = t & 63;
    int w = t >> 6;
    int col = lane & 15;
    int quad = lane >> 4;

    // --- per-lane staging SOURCE addresses (16B-chunk rotation folded in) ---
    // wave w stages its own 32 A-voxels (y-row y0+w) and oc rows [w*32, w*32+32)
    const b16* gAsrc[2];
    const b16* gBsrc[2];
    {
        int vsub = lane >> 2;            // 0..15: row within one 1KB instr
        int s    = lane & 3;             // 16B chunk slot this lane fills
        #pragma unroll
        for (int j = 0; j < 2; ++j) {
            int x  = j*16 + vsub;                        // A voxel x, 0..31
            int cA = (s - (x >> 1)) & 3;                 // global chunk for slot s
            gAsrc[j] = inp + ((long)((b*34 + z)*34 + (y0 + w))*34 + x)*IC + cA*8;
            int oc = w*32 + j*16 + vsub;
            int cB = (s - (vsub >> 1)) & 3;              // rot = ((oc&15)>>1) = vsub>>1
            gBsrc[j] = wt + oc*32 + cB*8;
        }
    }

    // --- fragment read offsets (r0-verified mapping) ---
    int so   = ((quad + (col>>1)) & 3) * 8;
    int aoff = w*1024 + col*32 + so;
    int boff = col*32 + so;

    v4f acc[2][8];
    #pragma unroll
    for (int tl=0;tl<2;++tl)
        #pragma unroll
        for (int n=0;n<8;++n) acc[tl][n] = (v4f){0.f,0.f,0.f,0.f};

    // --- tap-walk recurrence for A offsets (uniform scalars, no divides) ---
    long offAn = 0;                       // offset of the NEXT k-step to stage
    int icbn = 0, kxn = 0, kyn = 0;
    auto advance = [&]() {
        ++icbn; offAn += 32;
        if (icbn == ICB) {
            icbn = 0;
            ++kxn;
            if (kxn == 3) {
                kxn = 0; ++kyn;
                if (kyn == 3) { kyn = 0; offAn += (long)(34*34 - 2*34 - 3)*IC; }
                else          {           offAn += (long)(34 - 3)*IC; }
            }
        }
    };

    auto stage = [&](long offA, long offB, int buf) {
        #pragma unroll
        for (int j = 0; j < 2; ++j) {
            gll16(gAsrc[j] + offA, &lA[buf][w*1024 + j*512]);
            gll16(gBsrc[j] + offB, &lB[buf][w*1024 + j*512]);
        }
    };

    // prologue: stage k=0 into buf0
    stage(0, 0, 0);
    advance();                            // offAn -> offA(1)
    long offBn = 4096;
    __syncthreads();                      // drains vmcnt(0) before s_barrier

    int cur = 0;
    for (int k = 0; k < NK; ++k) {
        if (k + 1 < NK) {                 // issue next-tile DMA (overlaps MFMA)
            stage(offAn, offBn, cur ^ 1);
            advance();
            offBn += 4096;
        }
        v8s a0 = *(const v8s*)(&lA[cur][aoff]);
        v8s a1 = *(const v8s*)(&lA[cur][aoff + 512]);
        #pragma unroll
        for (int n = 0; n < 8; ++n) {
            v8s bb = *(const v8s*)(&lB[cur][n*512 + boff]);
            acc[0][n] = __builtin_amdgcn_mfma_f32_16x16x32_bf16(a0, bb, acc[0][n], 0,0,0);
            acc[1][n] = __builtin_amdgcn_mfma_f32_16x16x32_bf16(a1, bb, acc[1][n], 0,0,0);
        }
        __syncthreads();                  // drains vmcnt(0): staged buf cur^1 ready
        cur ^= 1;
    }

    int yrow = y0 + w;
    long cellrow = ((long)(b*32+z)*32 + yrow)*32;

    if (!IS_CONV1) {
        // skip GEMM: x_ds[cell][64] @ wst[128][64]^T folded into accumulators
        const b16* X0 = x_ds + (cellrow + col)*64 + quad*8;
        const b16* X1 = X0 + 16*64;
        const b16* WS = wst + col*64 + quad*8;
        #pragma unroll
        for (int s = 0; s < 2; ++s) {
            v8s a0 = *(const v8s*)(X0 + s*32);
            v8s a1 = *(const v8s*)(X1 + s*32);
            #pragma unroll
            for (int n=0;n<8;++n) {
                v8s bb = *(const v8s*)(WS + n*16*64 + s*32);
                acc[0][n] = __builtin_amdgcn_mfma_f32_16x16x32_bf16(a0, bb, acc[0][n], 0,0,0);
                acc[1][n] = __builtin_amdgcn_mfma_f32_16x16x32_bf16(a1, bb, acc[1][n], 0,0,0);
            }
        }
    }

    float bv[8];
    #pragma unroll
    for (int n=0;n<8;++n)
        bv[n] = bias[n*16+col] + (IS_CONV1 ? 0.f : b_skip[n*16+col]);

    long prow = ((long)(b*34 + z+1)*34 + (yrow+1))*34 + 1;

    #pragma unroll
    for (int tl=0; tl<2; ++tl) {
        if (IS_CONV1) {
            // bias + LN(128, no affine) + silu + mask -> padded bf16
            float s1[4], s2[4];
            #pragma unroll
            for (int r=0;r<4;++r){
                float a=0.f, q=0.f;
                #pragma unroll
                for (int n=0;n<8;++n){ float v = acc[tl][n][r] + bv[n]; a+=v; q+=v*v; }
                s1[r]=a; s2[r]=q;
            }
            #pragma unroll
            for (int off=1; off<16; off<<=1){
                #pragma unroll
                for (int r=0;r<4;++r){ s1[r]+=__shfl_xor(s1[r],off); s2[r]+=__shfl_xor(s2[r],off); }
            }
            #pragma unroll
            for (int r=0;r<4;++r){
                int row = quad*4 + r;
                int x = tl*16 + row;
                float c = cnt[cellrow + x];
                float mu = s1[r]*(1.f/128.f);
                float var = fmaxf(s2[r]*(1.f/128.f) - mu*mu, 0.f);
                float rs = rsqrtf(var + EPS);
                bool act = c > 0.f;
                #pragma unroll
                for (int n=0;n<8;++n){
                    float v = acc[tl][n][r] + bv[n];
                    float hv = act ? siluf((v-mu)*rs) : 0.f;
                    h2out[(prow + x)*128 + n*16 + col] = f2b(hv);
                }
            }
        } else {
            #pragma unroll
            for (int r=0;r<4;++r){
                int row = quad*4 + r;
                int x = tl*16 + row;
                float c = cnt[cellrow + x];
                bool act = c > 0.f;
                #pragma unroll
                for (int n=0;n<8;++n){
                    float v = acc[tl][n][r] + bv[n];
                    out[(cellrow + x)*128 + n*16 + col] = act ? v : 0.f;
                }
            }
        }
    }
}

// distinct names so rocprof separates the two convs; min 4 waves/EU forces
// <=128 regs/wave (incl. acc AGPRs, unified file) -> 4 blocks/CU
__global__ void __launch_bounds__(256, 4) k_conv1(
    const b16* __restrict__ inp, const b16* __restrict__ wt,
    const float* __restrict__ bias, const float* __restrict__ cnt,
    b16* __restrict__ h2out)
{
    conv_body<64, true>(inp, wt, bias, cnt, nullptr, nullptr, nullptr, h2out, nullptr);
}

__global__ void __launch_bounds__(256, 4) k_conv2(
    const b16* __restrict__ inp, const b16* __restrict__ wt,
    const float* __restrict__ bias, const float* __restrict__ cnt,
    const b16* __restrict__ x_ds, const b16* __restrict__ wst,
    const float* __restrict__ b_skip, float* __restrict__ out)
{
    conv_body<128, false>(inp, wt, bias, cnt, x_ds, wst, b_skip, nullptr, out);
}

extern "C" void kernel_launch(void* const* d_in, const int* in_sizes, int n_in,
                              void* d_out, int out_size, void* d_ws, size_t ws_size,
                              hipStream_t stream) {
    const float* feats  = (const float*)d_in[0];
    const int*   mask   = (const int*)  d_in[1];
    const float* gamma1 = (const float*)d_in[2];
    const float* beta1  = (const float*)d_in[3];
    const float* w1     = (const float*)d_in[4];
    const float* b1     = (const float*)d_in[5];
    const float* w2     = (const float*)d_in[6];
    const float* b2     = (const float*)d_in[7];
    const float* w_skip = (const float*)d_in[8];
    const float* b_skip = (const float*)d_in[9];
    float* out = (float*)d_out;

    char* ws = (char*)d_ws;
    b16*   h_ds_pad = (b16*)(ws);                        // 4*34^3*64*2  = 20,123,648
    b16*   h2_pad   = (b16*)(ws + 20123648);             // 4*34^3*128*2 = 40,247,296
    b16*   x_ds     = (b16*)(ws + 60370944);             // 16,777,216
    float* cnt      = (float*)(ws + 77148160);           // 524,288
    b16*   w1t      = (b16*)(ws + 77672448);             // 442,368
    b16*   w2t      = (b16*)(ws + 78114816);             // 884,736
    b16*   wst      = (b16*)(ws + 78999552);             // 16,384

    // zero halos (interior fully overwritten each launch)
    hipMemsetAsync(h_ds_pad, 0, 20123648, stream);
    hipMemsetAsync(h2_pad,   0, 40247296, stream);

    const int n_w1 = 27*64*128;    // 221184
    const int n_w2 = 27*128*128;   // 442368
    const int n_ws = 64*128;       // 8192
    k_wtb<64> <<<(n_w1 + 255)/256, 256, 0, stream>>>(w1, w1t, n_w1);
    k_wtb<128><<<(n_w2 + 255)/256, 256, 0, stream>>>(w2, w2t, n_w2);
    k_wt<64>  <<<(n_ws + 255)/256, 256, 0, stream>>>(w_skip, wst, n_ws);

    k_ln_down<<<32768, 256, 0, stream>>>(feats, mask, gamma1, beta1, h_ds_pad, x_ds, cnt);

    k_conv1<<<1024, 256, 0, stream>>>(h_ds_pad, w1t, b1, cnt, h2_pad);
    k_conv2<<<1024, 256, 0, stream>>>(h2_pad, w2t, b2, cnt, x_ds, wst, b_skip, out);
}